// Round 6
// baseline (797.470 us; speedup 1.0000x reference)
//
#include <hip/hip_runtime.h>
#include <hip/hip_cooperative_groups.h>
#include <math.h>

#define N_NODES   2000000
#define N_MOVABLE 1500000
#define N_FILLER  400000
#define N_NETS    1500000
#define N_PINS    (N_NETS * 4)
#define NB        512                  // bins per axis (cropped map)
#define NT        16                   // tiles per axis
#define TILE      32                   // bins per tile axis
#define NBUCKET   (NT * NT)            // 256
#define CAP       10240                // slab capacity per bucket
#define NMAPS     16                   // 4 quarters x 4 parities
#define NPB       4096                 // nets per gather block (4 per thread)
#define MEGA_BLOCKS 1024
#define GSZ       (MEGA_BLOCKS * 256)

namespace cg = cooperative_groups;

__device__ __forceinline__ int bin_idx(float v) {
    // BIN_W = 1000/512 = 1.953125 exactly; matches jnp floor(v / BIN_W)
    float b = floorf(v / 1.953125f);
    b = fminf(fmaxf(b, 0.0f), 511.0f);
    return (int)b;
}

// ---------------------------------------------------------------------------
// Stage 0: pack pin x/y halves into float2 (one line per gather) + zero g_ptr
// ---------------------------------------------------------------------------
__global__ void pack_kernel(const float* __restrict__ pin_pos,
                            float2* __restrict__ pp,
                            unsigned* __restrict__ g_ptr) {
    if (blockIdx.x == 0 && threadIdx.x < NBUCKET) g_ptr[threadIdx.x] = 0u;
    int i = blockIdx.x * blockDim.x + threadIdx.x;
    if (i >= N_PINS / 4) return;
    float4 a = reinterpret_cast<const float4*>(pin_pos)[i];
    float4 b = reinterpret_cast<const float4*>(pin_pos + N_PINS)[i];
    float4* o = reinterpret_cast<float4*>(pp + 4 * (size_t)i);
    o[0] = make_float4(a.x, b.x, a.y, b.y);
    o[1] = make_float4(a.z, b.z, a.w, b.w);
}

// ---------------------------------------------------------------------------
// Per-net record: {vh, vv, pack(blx,bly), pack(bhx+1,bhy+1)} + bucket id
// ---------------------------------------------------------------------------
template <bool PACKED>
__device__ __forceinline__ float4 make_rec(const float* __restrict__ pin_pos,
                                           const float2* __restrict__ pp,
                                           int4 fp, int* bucket) {
    float2 p0, p1, p2, p3;
    if (PACKED) {
        p0 = pp[fp.x]; p1 = pp[fp.y]; p2 = pp[fp.z]; p3 = pp[fp.w];
    } else {
        p0 = make_float2(pin_pos[fp.x], pin_pos[N_PINS + fp.x]);
        p1 = make_float2(pin_pos[fp.y], pin_pos[N_PINS + fp.y]);
        p2 = make_float2(pin_pos[fp.z], pin_pos[N_PINS + fp.z]);
        p3 = make_float2(pin_pos[fp.w], pin_pos[N_PINS + fp.w]);
    }
    float xl = fminf(fminf(p0.x, p1.x), fminf(p2.x, p3.x));
    float xh = fmaxf(fmaxf(p0.x, p1.x), fmaxf(p2.x, p3.x));
    float yl = fminf(fminf(p0.y, p1.y), fminf(p2.y, p3.y));
    float yh = fmaxf(fmaxf(p0.y, p1.y), fmaxf(p2.y, p3.y));
    float bw = xh - xl, bh = yh - yl;
    float barea = fmaxf(bw * bh, 1e-6f);
    float vh = (bw / barea) * (1.0f / 1.5f);   // fold /UNIT_H_CAP
    float vv = (bh / barea) * (1.0f / 1.5f);
    unsigned blx = bin_idx(xl), bhx = bin_idx(xh);
    unsigned bly = bin_idx(yl), bhy = bin_idx(yh);
    *bucket = (int)((bly >> 5) * NT + (blx >> 5));
    float4 r;
    r.x = vh; r.y = vv;
    r.z = __uint_as_float(blx | (bly << 16));
    r.w = __uint_as_float((bhx + 1) | ((bhy + 1) << 16));
    return r;
}

// ---------------------------------------------------------------------------
// Stage 1: gather + bucket (counting-sort into per-tile slabs), 4 nets/thread
// ---------------------------------------------------------------------------
template <bool PACKED>
__global__ __launch_bounds__(1024)
void gather_bin_kernel(const float* __restrict__ pin_pos,
                       const float2* __restrict__ pp,
                       const int*  __restrict__ fnp,
                       float4* __restrict__ slab,
                       unsigned* __restrict__ g_ptr) {
    __shared__ unsigned hist[NBUCKET];
    __shared__ unsigned base[NBUCKET];
    int t = threadIdx.x;
    if (t < NBUCKET) hist[t] = 0;
    __syncthreads();

    int n0 = blockIdx.x * NPB + t;
    bool v[4]; int4 fp[4]; float4 r[4]; int b[4]; unsigned rk[4];
    #pragma unroll
    for (int k = 0; k < 4; ++k) {
        int n = n0 + k * 1024;
        v[k] = (n < N_NETS);
        fp[k] = v[k] ? *reinterpret_cast<const int4*>(fnp + 4 * (size_t)n)
                     : make_int4(0, 0, 0, 0);
    }
    #pragma unroll
    for (int k = 0; k < 4; ++k) {
        b[k] = 0;
        if (v[k]) r[k] = make_rec<PACKED>(pin_pos, pp, fp[k], &b[k]);
    }
    #pragma unroll
    for (int k = 0; k < 4; ++k) {
        rk[k] = v[k] ? atomicAdd(&hist[b[k]], 1u) : 0u;
    }
    __syncthreads();
    if (t < NBUCKET) {
        unsigned c = hist[t];
        base[t] = c ? atomicAdd(&g_ptr[t], c) : 0u;
    }
    __syncthreads();
    #pragma unroll
    for (int k = 0; k < 4; ++k) {
        if (v[k]) {
            unsigned s = base[b[k]] + rk[k];
            if (s < CAP) slab[(size_t)b[k] * CAP + s] = r[k];
        }
    }
}

// ---------------------------------------------------------------------------
// Stage functions (shared by the cooperative mega-kernel and discrete fallback)
// ---------------------------------------------------------------------------

// accum: wg = bucket*4 + quarter. 64x64 halo in LDS, each record read ONCE.
// Output map m = quarter*4 + (ty&1)*2 + (tx&1): same-parity same-quarter halos
// are disjoint -> plain stores, no global atomics. Corner coords ==512 cropped.
__device__ __forceinline__ void stage_accum(const float4* __restrict__ slab,
                                            const unsigned* __restrict__ g_cnt,
                                            float2* __restrict__ Dp,
                                            float2* acc, int wg, int tid) {
    int h = wg & 3, tile = wg >> 2;
    int tx = tile & (NT - 1), ty = tile >> 4;

    for (int i = tid; i < 64 * 64; i += 256) acc[i] = make_float2(0.f, 0.f);
    __syncthreads();

    int x0 = tx * TILE, y0 = ty * TILE;
    unsigned cnt = min(g_cnt[tile], (unsigned)CAP);
    unsigned lo = (cnt * (unsigned)h) >> 2;
    unsigned hi = (cnt * (unsigned)(h + 1)) >> 2;
    const float4* recs = slab + (size_t)tile * CAP;

    for (unsigned i = lo + tid; i < hi; i += 256) {
        float4 r = recs[i];
        unsigned zlo = __float_as_uint(r.z), zhi = __float_as_uint(r.w);
        int ax0 = (int)(zlo & 0xffffu), ay0 = (int)(zlo >> 16);
        int ax1 = (int)(zhi & 0xffffu), ay1 = (int)(zhi >> 16);
        int X0 = ax0 - x0, Y0 = ay0 - y0;
        int X1 = ax1 - x0, Y1 = ay1 - y0;
        bool okx1 = (ax1 < NB), oky1 = (ay1 < NB);
        atomicAdd(&acc[X0 * 64 + Y0].x,  r.x);
        atomicAdd(&acc[X0 * 64 + Y0].y,  r.y);
        if (okx1) { atomicAdd(&acc[X1 * 64 + Y0].x, -r.x); atomicAdd(&acc[X1 * 64 + Y0].y, -r.y); }
        if (oky1) { atomicAdd(&acc[X0 * 64 + Y1].x, -r.x); atomicAdd(&acc[X0 * 64 + Y1].y, -r.y); }
        if (okx1 && oky1) { atomicAdd(&acc[X1 * 64 + Y1].x, r.x); atomicAdd(&acc[X1 * 64 + Y1].y, r.y); }
    }
    __syncthreads();

    int m = h * 4 + (ty & 1) * 2 + (tx & 1);
    float2* D = Dp + (size_t)m * NB * NB;
    for (int i = tid; i < 64 * 64; i += 256) {
        int X = i >> 6, Y = i & 63;
        int gx = x0 + X, gy = y0 + Y;
        if (gx < NB && gy < NB) D[(size_t)gx * NB + gy] = acc[i];
    }
}

// scanA: cumsum along y; sums 16 parity maps on load (coalesced).
// Maps with tx-parity 1 never write x<32; ty-parity 1 never write y<32.
__device__ __forceinline__ void stage_scanA(const float2* __restrict__ Dp,
                                            float2* __restrict__ S,
                                            float2* s, int x, int tid) {
    #pragma unroll
    for (int k = 0; k < 2; ++k) {
        int y = tid + k * 256;
        float2 a = make_float2(0.f, 0.f);
        #pragma unroll
        for (int m = 0; m < NMAPS; ++m) {
            if (((m & 1) && x < TILE) || ((m & 2) && y < TILE)) continue;
            float2 v = Dp[(size_t)m * NB * NB + (size_t)x * NB + y];
            a.x += v.x; a.y += v.y;
        }
        s[y] = a;
    }
    __syncthreads();
    for (int off = 1; off < NB; off <<= 1) {
        float2 u0 = s[tid], u1 = s[tid + 256];
        float2 w0 = (tid >= off) ? s[tid - off] : make_float2(0.f, 0.f);
        float2 w1 = s[tid + 256 - off];
        __syncthreads();
        if (tid >= off) { u0.x += w0.x; u0.y += w0.y; }
        u1.x += w1.x; u1.y += w1.y;
        s[tid] = u0; s[tid + 256] = u1;
        __syncthreads();
    }
    S[(size_t)x * NB + tid] = s[tid];
    S[(size_t)x * NB + tid + 256] = s[tid + 256];
}

// scanB: cumsum along x (strided single-map pass)
__device__ __forceinline__ void stage_scanB(float2* __restrict__ S,
                                            float2* s, int y, int tid) {
    s[tid] = S[(size_t)tid * NB + y];
    s[tid + 256] = S[(size_t)(tid + 256) * NB + y];
    __syncthreads();
    for (int off = 1; off < NB; off <<= 1) {
        float2 u0 = s[tid], u1 = s[tid + 256];
        float2 w0 = (tid >= off) ? s[tid - off] : make_float2(0.f, 0.f);
        float2 w1 = s[tid + 256 - off];
        __syncthreads();
        if (tid >= off) { u0.x += w0.x; u0.y += w0.y; }
        u1.x += w1.x; u1.y += w1.y;
        s[tid] = u0; s[tid + 256] = u1;
        __syncthreads();
    }
    S[(size_t)tid * NB + y] = s[tid];
    S[(size_t)(tid + 256) * NB + y] = s[tid + 256];
}

__device__ __forceinline__ void stage_reduce(const float* __restrict__ pos,
                                             const float* __restrict__ nsx,
                                             const float* __restrict__ nsy,
                                             const float2* __restrict__ S,
                                             double* __restrict__ partials,
                                             float2* smem, int bid, int tid) {
    const int MQ = N_MOVABLE / 4;            // 375000
    const int TQ = MQ + N_FILLER / 4;        // 475000
    double a_old = 0.0, a_route = 0.0, a_fill = 0.0;
    for (int q = bid * 256 + tid; q < TQ; q += GSZ) {
        if (q < MQ) {
            int i = 4 * q;
            float4 x4  = *reinterpret_cast<const float4*>(pos + i);
            float4 y4  = *reinterpret_cast<const float4*>(pos + N_NODES + i);
            float4 sx4 = *reinterpret_cast<const float4*>(nsx + i);
            float4 sy4 = *reinterpret_cast<const float4*>(nsy + i);
            float xs[4] = {x4.x, x4.y, x4.z, x4.w};
            float ys[4] = {y4.x, y4.y, y4.z, y4.w};
            float sxs[4] = {sx4.x, sx4.y, sx4.z, sx4.w};
            float sys[4] = {sy4.x, sy4.y, sy4.z, sy4.w};
            #pragma unroll
            for (int k = 0; k < 4; ++k) {
                int bx = bin_idx(xs[k] + 0.5f * sxs[k]);
                int by = bin_idx(ys[k] + 0.5f * sys[k]);
                float2 u2 = S[(size_t)bx * NB + by];
                float ratio = fminf(fmaxf(fmaxf(u2.x, u2.y), 0.5f), 2.0f);
                float area = sxs[k] * sys[k];
                a_old += (double)area;
                a_route += (double)(area * ratio);
            }
        } else {
            int j = (N_NODES - N_FILLER) + 4 * (q - MQ);
            float4 sx4 = *reinterpret_cast<const float4*>(nsx + j);
            float4 sy4 = *reinterpret_cast<const float4*>(nsy + j);
            a_fill += (double)(sx4.x * sy4.x + sx4.y * sy4.y +
                               sx4.z * sy4.z + sx4.w * sy4.w);
        }
    }
    for (int off = 32; off > 0; off >>= 1) {
        a_old   += __shfl_down(a_old, off);
        a_route += __shfl_down(a_route, off);
        a_fill  += __shfl_down(a_fill, off);
    }
    double* sd = (double*)smem;   // 4 waves x 3
    int wid = tid >> 6, lane = tid & 63;
    if (lane == 0) { sd[wid * 3 + 0] = a_old; sd[wid * 3 + 1] = a_route; sd[wid * 3 + 2] = a_fill; }
    __syncthreads();
    if (tid == 0) {
        double s0 = 0, s1 = 0, s2 = 0;
        for (int w = 0; w < 4; ++w) { s0 += sd[w * 3]; s1 += sd[w * 3 + 1]; s2 += sd[w * 3 + 2]; }
        partials[bid * 3 + 0] = s0;
        partials[bid * 3 + 1] = s1;
        partials[bid * 3 + 2] = s2;
    }
}

__device__ __forceinline__ void stage_finish(const double* __restrict__ partials,
                                             double* __restrict__ sums,
                                             float2* smem, int tid) {
    double s0 = 0, s1 = 0, s2 = 0;
    for (int r = tid; r < MEGA_BLOCKS; r += 256) {
        s0 += partials[r * 3 + 0];
        s1 += partials[r * 3 + 1];
        s2 += partials[r * 3 + 2];
    }
    for (int off = 32; off > 0; off >>= 1) {
        s0 += __shfl_down(s0, off);
        s1 += __shfl_down(s1, off);
        s2 += __shfl_down(s2, off);
    }
    double* sd = (double*)smem;
    int wid = tid >> 6, lane = tid & 63;
    if (lane == 0) { sd[wid * 3 + 0] = s0; sd[wid * 3 + 1] = s1; sd[wid * 3 + 2] = s2; }
    __syncthreads();
    if (tid == 0) {
        double a = 0, b = 0, c = 0;
        for (int w = 0; w < 4; ++w) { a += sd[w * 3]; b += sd[w * 3 + 1]; c += sd[w * 3 + 2]; }
        sums[0] = a; sums[1] = b; sums[2] = c;
    }
}

__device__ __forceinline__ void stage_final(const float* __restrict__ pos,
                                            const float* __restrict__ nsx,
                                            const float* __restrict__ nsy,
                                            const float2* __restrict__ S,
                                            const double* __restrict__ sums,
                                            float* __restrict__ out,
                                            int bid, int tid) {
    double sum_area  = sums[0];
    double sum_route = sums[1];
    double fill_old  = sums[2];
    double max_total = sum_area + fill_old;
    float scale = fminf(1.0f, (float)(max_total / fmax(sum_route, 1e-6)));
    float sum_new = (float)(scale * (float)sum_route);
    float fscale = sqrtf(fmaxf((float)max_total - sum_new, 0.0f) /
                         fmaxf((float)fill_old, 1e-6f));

    for (int q = bid * 256 + tid; q < N_NODES / 4; q += GSZ) {
        int i = 4 * q;
        float4 x4  = *reinterpret_cast<const float4*>(pos + i);
        float4 y4  = *reinterpret_cast<const float4*>(pos + N_NODES + i);
        float4 sx4 = *reinterpret_cast<const float4*>(nsx + i);
        float4 sy4 = *reinterpret_cast<const float4*>(nsy + i);
        float xs[4] = {x4.x, x4.y, x4.z, x4.w};
        float ys[4] = {y4.x, y4.y, y4.z, y4.w};
        float sxs[4] = {sx4.x, sx4.y, sx4.z, sx4.w};
        float sys[4] = {sy4.x, sy4.y, sy4.z, sy4.w};

        if (i < N_MOVABLE) {
            #pragma unroll
            for (int k = 0; k < 4; ++k) {
                int bx = bin_idx(xs[k] + 0.5f * sxs[k]);
                int by = bin_idx(ys[k] + 0.5f * sys[k]);
                float2 u2 = S[(size_t)bx * NB + by];
                float ratio = fminf(fmaxf(fmaxf(u2.x, u2.y), 0.5f), 2.0f);
                float area = sxs[k] * sys[k];
                float new_area = area * ratio * scale;
                float sr = sqrtf(new_area / fmaxf(area, 1e-6f));
                float sx_new = sxs[k] * sr, sy_new = sys[k] * sr;
                xs[k] = xs[k] + 0.5f * (sxs[k] - sx_new);
                ys[k] = ys[k] + 0.5f * (sys[k] - sy_new);
                sxs[k] = sx_new; sys[k] = sy_new;
            }
        } else if (i >= N_NODES - N_FILLER) {
            #pragma unroll
            for (int k = 0; k < 4; ++k) { sxs[k] *= fscale; sys[k] *= fscale; }
        }

        *reinterpret_cast<float4*>(out + i)               = make_float4(xs[0], xs[1], xs[2], xs[3]);
        *reinterpret_cast<float4*>(out + N_NODES + i)     = make_float4(ys[0], ys[1], ys[2], ys[3]);
        *reinterpret_cast<float4*>(out + 2 * N_NODES + i) = make_float4(sxs[0], sxs[1], sxs[2], sxs[3]);
        *reinterpret_cast<float4*>(out + 3 * N_NODES + i) = make_float4(sys[0], sys[1], sys[2], sys[3]);
    }
}

// ---------------------------------------------------------------------------
// Cooperative mega-kernel: accum -> scanA -> scanB -> reduce -> finish -> final
// ---------------------------------------------------------------------------
__global__ __launch_bounds__(256)
void mega_kernel(const float4* __restrict__ slab,
                 const unsigned* __restrict__ g_cnt,
                 float2* __restrict__ Dp,
                 float2* __restrict__ S,
                 const float* __restrict__ pos,
                 const float* __restrict__ nsx,
                 const float* __restrict__ nsy,
                 double* __restrict__ partials,
                 double* __restrict__ sums,
                 float* __restrict__ out) {
    __shared__ float2 smem[4096];   // 32 KB, reused per stage
    cg::grid_group g = cg::this_grid();
    int bid = blockIdx.x, tid = threadIdx.x;

    stage_accum(slab, g_cnt, Dp, smem, bid, tid);
    g.sync();
    if (bid < NB) stage_scanA(Dp, S, smem, bid, tid);
    g.sync();
    if (bid < NB) stage_scanB(S, smem, bid, tid);
    g.sync();
    stage_reduce(pos, nsx, nsy, S, partials, smem, bid, tid);
    g.sync();
    if (bid == 0) stage_finish(partials, sums, smem, tid);
    g.sync();
    stage_final(pos, nsx, nsy, S, sums, out, bid, tid);
}

// ---------------------------------------------------------------------------
// Discrete fallback wrappers (same stage code, separate dispatches)
// ---------------------------------------------------------------------------
__global__ __launch_bounds__(256)
void accum_kernel(const float4* __restrict__ slab, const unsigned* __restrict__ g_cnt,
                  float2* __restrict__ Dp) {
    __shared__ float2 smem[4096];
    stage_accum(slab, g_cnt, Dp, smem, blockIdx.x, threadIdx.x);
}
__global__ __launch_bounds__(256)
void scanA_kernel(const float2* __restrict__ Dp, float2* __restrict__ S) {
    __shared__ float2 s[NB];
    stage_scanA(Dp, S, s, blockIdx.x, threadIdx.x);
}
__global__ __launch_bounds__(256)
void scanB_kernel(float2* __restrict__ S) {
    __shared__ float2 s[NB];
    stage_scanB(S, s, blockIdx.x, threadIdx.x);
}
__global__ __launch_bounds__(256)
void reduce_kernel(const float* __restrict__ pos, const float* __restrict__ nsx,
                   const float* __restrict__ nsy, const float2* __restrict__ S,
                   double* __restrict__ partials) {
    __shared__ float2 smem[64];
    stage_reduce(pos, nsx, nsy, S, partials, smem, blockIdx.x, threadIdx.x);
}
__global__ __launch_bounds__(256)
void finish_kernel(const double* __restrict__ partials, double* __restrict__ sums) {
    __shared__ float2 smem[64];
    stage_finish(partials, sums, smem, threadIdx.x);
}
__global__ __launch_bounds__(256)
void final_kernel(const float* __restrict__ pos, const float* __restrict__ nsx,
                  const float* __restrict__ nsy, const float2* __restrict__ S,
                  const double* __restrict__ sums, float* __restrict__ out) {
    stage_final(pos, nsx, nsy, S, sums, out, blockIdx.x, threadIdx.x);
}

// ---------------------------------------------------------------------------
extern "C" void kernel_launch(void* const* d_in, const int* in_sizes, int n_in,
                              void* d_out, int out_size, void* d_ws, size_t ws_size,
                              hipStream_t stream) {
    const float* pos         = (const float*)d_in[0];
    const float* pin_pos     = (const float*)d_in[1];
    const float* nsx         = (const float*)d_in[2];
    const float* nsy         = (const float*)d_in[3];
    const int*   flat_netpin = (const int*)d_in[4];
    float* out = (float*)d_out;

    const size_t pp_b   = (size_t)N_PINS * sizeof(float2);             // 48 MB
    const size_t slab_b = (size_t)NBUCKET * CAP * sizeof(float4);      // 40 MB
    const size_t dp_b   = (size_t)NMAPS * NB * NB * sizeof(float2);    // 32 MB
    const size_t s_b    = (size_t)NB * NB * sizeof(float2);            // 2 MB
    const size_t part_b = (size_t)MEGA_BLOCKS * 3 * sizeof(double);    // 24 KB
    const size_t gp_b   = 4096;

    // Primary layout: [pp(48) | slab(40) | g_ptr | ..]. Dp/S/partials/sums
    // overlay pp (dead after gather); dp_b+s_b+part_b+32 = ~35.7 MB <= 48 MB.
    const size_t need_primary = pp_b + slab_b + gp_b + 256;

    char* base = (char*)d_ws;
    bool packed = (ws_size >= need_primary);

    float2* pp; float4* slab; float2* Dp; float2* S;
    double* partials; double* sums; unsigned* g_ptr;
    if (packed) {
        pp       = (float2*)base;
        Dp       = (float2*)base;                       // overlay after gather
        S        = (float2*)(base + dp_b);
        partials = (double*)(base + dp_b + s_b);
        sums     = (double*)(base + dp_b + s_b + part_b);
        slab     = (float4*)(base + pp_b);
        g_ptr    = (unsigned*)(base + pp_b + slab_b);
    } else {
        pp       = nullptr;
        slab     = (float4*)base;
        Dp       = (float2*)(base + slab_b);
        S        = (float2*)(base + slab_b + dp_b);
        partials = (double*)(base + slab_b + dp_b + s_b);
        sums     = (double*)(base + slab_b + dp_b + s_b + part_b);
        g_ptr    = (unsigned*)(base + slab_b + dp_b + s_b + part_b + 64);
    }

    const int GB_BLOCKS = (N_NETS + NPB - 1) / NPB;    // 367
    if (packed) {
        pack_kernel<<<(N_PINS / 4 + 255) / 256, 256, 0, stream>>>(pin_pos, pp, g_ptr);
        gather_bin_kernel<true><<<GB_BLOCKS, 1024, 0, stream>>>(pin_pos, pp, flat_netpin, slab, g_ptr);
    } else {
        hipMemsetAsync(g_ptr, 0, NBUCKET * sizeof(unsigned), stream);
        gather_bin_kernel<false><<<GB_BLOCKS, 1024, 0, stream>>>(pin_pos, nullptr, flat_netpin, slab, g_ptr);
    }

    // Cooperative tail; clean fallback to discrete chain if rejected.
    const float4* slab_c = slab;
    const unsigned* gc = g_ptr;
    const float* pos_c = pos; const float* nsx_c = nsx; const float* nsy_c = nsy;
    float* out_l = out;
    void* args[] = { (void*)&slab_c, (void*)&gc, (void*)&Dp, (void*)&S,
                     (void*)&pos_c, (void*)&nsx_c, (void*)&nsy_c,
                     (void*)&partials, (void*)&sums, (void*)&out_l };
    hipError_t e = hipLaunchCooperativeKernel((void*)mega_kernel,
                                              dim3(MEGA_BLOCKS), dim3(256),
                                              args, 0, stream);
    if (e != hipSuccess) {
        (void)hipGetLastError();   // clear sticky error
        accum_kernel <<<MEGA_BLOCKS, 256, 0, stream>>>(slab, g_ptr, Dp);
        scanA_kernel <<<NB, 256, 0, stream>>>(Dp, S);
        scanB_kernel <<<NB, 256, 0, stream>>>(S);
        reduce_kernel<<<MEGA_BLOCKS, 256, 0, stream>>>(pos, nsx, nsy, S, partials);
        finish_kernel<<<1, 256, 0, stream>>>(partials, sums);
        final_kernel <<<MEGA_BLOCKS, 256, 0, stream>>>(pos, nsx, nsy, S, sums, out);
    }
}

// Round 7
// 242.141 us; speedup vs baseline: 3.2934x; 3.2934x over previous
//
#include <hip/hip_runtime.h>
#include <math.h>

#define N_NODES   2000000
#define N_MOVABLE 1500000
#define N_FILLER  400000
#define N_NETS    1500000
#define N_PINS    (N_NETS * 4)
#define NB        512                  // bins per axis (cropped map)
#define NT        16                   // tiles per axis
#define TILE      32                   // bins per tile axis
#define NBUCKET   (NT * NT)            // 256
#define CAP       10240                // slab capacity per bucket
#define NSLICE    4                    // record slices per tile
#define NMAPS     NSLICE               // partial diff maps (disjoint windows)
#define NPB       4096                 // nets per gather block (4 per thread)
#define RED_BLOCKS 1024

__device__ __forceinline__ int bin_idx(float v) {
    // BIN_W = 1000/512 = 1.953125 exactly; matches jnp floor(v / BIN_W)
    float b = floorf(v / 1.953125f);
    b = fminf(fmaxf(b, 0.0f), 511.0f);
    return (int)b;
}

// ---------------------------------------------------------------------------
// Stage 0: pack pin x/y halves into float2 (one line per gather) + zero g_ptr
// ---------------------------------------------------------------------------
__global__ void pack_kernel(const float* __restrict__ pin_pos,
                            float2* __restrict__ pp,
                            unsigned* __restrict__ g_ptr) {
    if (blockIdx.x == 0 && threadIdx.x < NBUCKET) g_ptr[threadIdx.x] = 0u;
    int i = blockIdx.x * blockDim.x + threadIdx.x;
    if (i >= N_PINS / 4) return;
    float4 a = reinterpret_cast<const float4*>(pin_pos)[i];
    float4 b = reinterpret_cast<const float4*>(pin_pos + N_PINS)[i];
    float4* o = reinterpret_cast<float4*>(pp + 4 * (size_t)i);
    o[0] = make_float4(a.x, b.x, a.y, b.y);
    o[1] = make_float4(a.z, b.z, a.w, b.w);
}

// ---------------------------------------------------------------------------
// Per-net record: {vh, vv, pack(blx,bly), pack(bhx+1,bhy+1)} + bucket id
// ---------------------------------------------------------------------------
template <bool PACKED>
__device__ __forceinline__ float4 make_rec(const float* __restrict__ pin_pos,
                                           const float2* __restrict__ pp,
                                           int4 fp, int* bucket) {
    float2 p0, p1, p2, p3;
    if (PACKED) {
        p0 = pp[fp.x]; p1 = pp[fp.y]; p2 = pp[fp.z]; p3 = pp[fp.w];
    } else {
        p0 = make_float2(pin_pos[fp.x], pin_pos[N_PINS + fp.x]);
        p1 = make_float2(pin_pos[fp.y], pin_pos[N_PINS + fp.y]);
        p2 = make_float2(pin_pos[fp.z], pin_pos[N_PINS + fp.z]);
        p3 = make_float2(pin_pos[fp.w], pin_pos[N_PINS + fp.w]);
    }
    float xl = fminf(fminf(p0.x, p1.x), fminf(p2.x, p3.x));
    float xh = fmaxf(fmaxf(p0.x, p1.x), fmaxf(p2.x, p3.x));
    float yl = fminf(fminf(p0.y, p1.y), fminf(p2.y, p3.y));
    float yh = fmaxf(fmaxf(p0.y, p1.y), fmaxf(p2.y, p3.y));
    float bw = xh - xl, bh = yh - yl;
    float barea = fmaxf(bw * bh, 1e-6f);
    float vh = (bw / barea) * (1.0f / 1.5f);   // fold /UNIT_H_CAP
    float vv = (bh / barea) * (1.0f / 1.5f);
    unsigned blx = bin_idx(xl), bhx = bin_idx(xh);
    unsigned bly = bin_idx(yl), bhy = bin_idx(yh);
    *bucket = (int)((bly >> 5) * NT + (blx >> 5));
    float4 r;
    r.x = vh; r.y = vv;
    r.z = __uint_as_float(blx | (bly << 16));
    r.w = __uint_as_float((bhx + 1) | ((bhy + 1) << 16));
    return r;
}

// ---------------------------------------------------------------------------
// Stage 1: gather + bucket (counting-sort into per-tile slabs), 4 nets/thread
// ---------------------------------------------------------------------------
template <bool PACKED>
__global__ __launch_bounds__(1024)
void gather_bin_kernel(const float* __restrict__ pin_pos,
                       const float2* __restrict__ pp,
                       const int*  __restrict__ fnp,
                       float4* __restrict__ slab,
                       unsigned* __restrict__ g_ptr) {
    __shared__ unsigned hist[NBUCKET];
    __shared__ unsigned base[NBUCKET];
    int t = threadIdx.x;
    if (t < NBUCKET) hist[t] = 0;
    __syncthreads();

    int n0 = blockIdx.x * NPB + t;
    bool v[4]; int4 fp[4]; float4 r[4]; int b[4]; unsigned rk[4];
    #pragma unroll
    for (int k = 0; k < 4; ++k) {
        int n = n0 + k * 1024;
        v[k] = (n < N_NETS);
        fp[k] = v[k] ? *reinterpret_cast<const int4*>(fnp + 4 * (size_t)n)
                     : make_int4(0, 0, 0, 0);
    }
    #pragma unroll
    for (int k = 0; k < 4; ++k) {
        b[k] = 0;
        if (v[k]) r[k] = make_rec<PACKED>(pin_pos, pp, fp[k], &b[k]);
    }
    #pragma unroll
    for (int k = 0; k < 4; ++k) {
        rk[k] = v[k] ? atomicAdd(&hist[b[k]], 1u) : 0u;
    }
    __syncthreads();
    if (t < NBUCKET) {
        unsigned c = hist[t];
        base[t] = c ? atomicAdd(&g_ptr[t], c) : 0u;
    }
    __syncthreads();
    #pragma unroll
    for (int k = 0; k < 4; ++k) {
        if (v[k]) {
            unsigned s = base[b[k]] + rk[k];
            if (s < CAP) slab[(size_t)b[k] * CAP + s] = r[k];
        }
    }
}

// ---------------------------------------------------------------------------
// Stage 2: per-tile accumulation in LDS. wg = tile*NSLICE + slice.
// Each wg reads slice [cnt*s/4, cnt*(s+1)/4) of its 4 source buckets
// ({tx-1,tx} x {ty-1,ty}: bbox span <= 22 bins), tests the 4 corners
// against its own 32x32 window, accumulates in 8 KB LDS, and writes the
// window to partial map `slice` with plain stores (windows are disjoint
// and tile the plane -> every map fully covered, no masks, no atomics).
// Corner coords ==512 drop out of every window (cropped).
// 4-deep load pipeline to cover slab-read latency.
// ---------------------------------------------------------------------------
__device__ __forceinline__ void rec_process(float4 r, int x0, int y0,
                                            float2* acc) {
    unsigned zlo = __float_as_uint(r.z), zhi = __float_as_uint(r.w);
    int ax0 = (int)(zlo & 0xffffu), ay0 = (int)(zlo >> 16);
    int ax1 = (int)(zhi & 0xffffu), ay1 = (int)(zhi >> 16);
    int X0 = ax0 - x0, Y0 = ay0 - y0;
    int X1 = ax1 - x0, Y1 = ay1 - y0;
    bool iX0 = (unsigned)X0 < TILE, iX1 = (unsigned)X1 < TILE;
    bool iY0 = (unsigned)Y0 < TILE, iY1 = (unsigned)Y1 < TILE;
    if (iX0 && iY0) { atomicAdd(&acc[X0 * TILE + Y0].x,  r.x); atomicAdd(&acc[X0 * TILE + Y0].y,  r.y); }
    if (iX1 && iY0) { atomicAdd(&acc[X1 * TILE + Y0].x, -r.x); atomicAdd(&acc[X1 * TILE + Y0].y, -r.y); }
    if (iX0 && iY1) { atomicAdd(&acc[X0 * TILE + Y1].x, -r.x); atomicAdd(&acc[X0 * TILE + Y1].y, -r.y); }
    if (iX1 && iY1) { atomicAdd(&acc[X1 * TILE + Y1].x,  r.x); atomicAdd(&acc[X1 * TILE + Y1].y,  r.y); }
}

__global__ __launch_bounds__(256)
void accum_kernel(const float4* __restrict__ slab,
                  const unsigned* __restrict__ g_cnt,
                  float2* __restrict__ Dp) {
    __shared__ float2 acc[TILE * TILE];       // 8 KB
    int wg = blockIdx.x;                       // 0..1023
    int sl = wg & (NSLICE - 1), tile = wg >> 2;
    int tx = tile & (NT - 1), ty = tile >> 4;
    int tid = threadIdx.x;

    for (int i = tid; i < TILE * TILE; i += 256) acc[i] = make_float2(0.f, 0.f);
    __syncthreads();

    int x0 = tx * TILE, y0 = ty * TILE;
    #pragma unroll
    for (int dy = -1; dy <= 0; ++dy) {
        int sy = ty + dy; if (sy < 0) continue;
        #pragma unroll
        for (int dx = -1; dx <= 0; ++dx) {
            int sx = tx + dx; if (sx < 0) continue;
            int sb = sy * NT + sx;
            unsigned cnt = min(g_cnt[sb], (unsigned)CAP);
            unsigned lo = (cnt * (unsigned)sl) >> 2;
            unsigned hi = (cnt * (unsigned)(sl + 1)) >> 2;
            const float4* recs = slab + (size_t)sb * CAP;
            unsigned i = lo + tid;
            for (; i + 768 < hi; i += 1024) {        // 4-deep pipeline
                float4 r0 = recs[i];
                float4 r1 = recs[i + 256];
                float4 r2 = recs[i + 512];
                float4 r3 = recs[i + 768];
                rec_process(r0, x0, y0, acc);
                rec_process(r1, x0, y0, acc);
                rec_process(r2, x0, y0, acc);
                rec_process(r3, x0, y0, acc);
            }
            for (; i < hi; i += 256) rec_process(recs[i], x0, y0, acc);
        }
    }
    __syncthreads();

    float2* D = Dp + (size_t)sl * NB * NB;
    for (int i = tid; i < TILE * TILE; i += 256) {
        int X = i >> 5, Y = i & 31;
        D[(size_t)(x0 + X) * NB + (y0 + Y)] = acc[i];
    }
}

// ---------------------------------------------------------------------------
// Stage 3a: cumsum along y; sums the 4 slice maps on load (coalesced).
// ---------------------------------------------------------------------------
__global__ __launch_bounds__(512)
void scanA_kernel(const float2* __restrict__ Dp, float2* __restrict__ S) {
    __shared__ float2 s[NB];
    int x = blockIdx.x, t = threadIdx.x;
    float2 a = make_float2(0.f, 0.f);
    #pragma unroll
    for (int m = 0; m < NMAPS; ++m) {
        float2 v = Dp[(size_t)m * NB * NB + (size_t)x * NB + t];
        a.x += v.x; a.y += v.y;
    }
    s[t] = a;
    __syncthreads();
    for (int off = 1; off < NB; off <<= 1) {
        float2 u = s[t];
        if (t >= off) { float2 w = s[t - off]; u.x += w.x; u.y += w.y; }
        __syncthreads();
        s[t] = u;
        __syncthreads();
    }
    S[(size_t)x * NB + t] = s[t];
}

// Stage 3b: cumsum along x (strided single-map pass; 2 MB L2-resident)
__global__ __launch_bounds__(512)
void scanB_kernel(float2* __restrict__ S) {
    __shared__ float2 s[NB];
    int y = blockIdx.x, t = threadIdx.x;
    s[t] = S[(size_t)t * NB + y];
    __syncthreads();
    for (int off = 1; off < NB; off <<= 1) {
        float2 u = s[t];
        if (t >= off) { float2 w = s[t - off]; u.x += w.x; u.y += w.y; }
        __syncthreads();
        s[t] = u;
        __syncthreads();
    }
    S[(size_t)t * NB + y] = s[t];
}

// ---------------------------------------------------------------------------
// Stage 4: reductions (float4 quads) -> per-block partials, then finish
// ---------------------------------------------------------------------------
__global__ __launch_bounds__(256)
void reduce_kernel(const float* __restrict__ pos,
                   const float* __restrict__ nsx,
                   const float* __restrict__ nsy,
                   const float2* __restrict__ S,
                   double* __restrict__ partials) {
    const int MQ = N_MOVABLE / 4;            // 375000
    const int TQ = MQ + N_FILLER / 4;        // 475000
    double a_old = 0.0, a_route = 0.0, a_fill = 0.0;
    int stride = gridDim.x * blockDim.x;
    for (int q = blockIdx.x * blockDim.x + threadIdx.x; q < TQ; q += stride) {
        if (q < MQ) {
            int i = 4 * q;
            float4 x4  = *reinterpret_cast<const float4*>(pos + i);
            float4 y4  = *reinterpret_cast<const float4*>(pos + N_NODES + i);
            float4 sx4 = *reinterpret_cast<const float4*>(nsx + i);
            float4 sy4 = *reinterpret_cast<const float4*>(nsy + i);
            float xs[4] = {x4.x, x4.y, x4.z, x4.w};
            float ys[4] = {y4.x, y4.y, y4.z, y4.w};
            float sxs[4] = {sx4.x, sx4.y, sx4.z, sx4.w};
            float sys[4] = {sy4.x, sy4.y, sy4.z, sy4.w};
            #pragma unroll
            for (int k = 0; k < 4; ++k) {
                int bx = bin_idx(xs[k] + 0.5f * sxs[k]);
                int by = bin_idx(ys[k] + 0.5f * sys[k]);
                float2 u2 = S[(size_t)bx * NB + by];
                float ratio = fminf(fmaxf(fmaxf(u2.x, u2.y), 0.5f), 2.0f);
                float area = sxs[k] * sys[k];
                a_old += (double)area;
                a_route += (double)(area * ratio);
            }
        } else {
            int j = (N_NODES - N_FILLER) + 4 * (q - MQ);
            float4 sx4 = *reinterpret_cast<const float4*>(nsx + j);
            float4 sy4 = *reinterpret_cast<const float4*>(nsy + j);
            a_fill += (double)(sx4.x * sy4.x + sx4.y * sy4.y +
                               sx4.z * sy4.z + sx4.w * sy4.w);
        }
    }
    for (int off = 32; off > 0; off >>= 1) {
        a_old   += __shfl_down(a_old, off);
        a_route += __shfl_down(a_route, off);
        a_fill  += __shfl_down(a_fill, off);
    }
    __shared__ double sd[4][3];
    int wid = threadIdx.x >> 6, lane = threadIdx.x & 63;
    if (lane == 0) { sd[wid][0] = a_old; sd[wid][1] = a_route; sd[wid][2] = a_fill; }
    __syncthreads();
    if (threadIdx.x == 0) {
        double s0 = 0, s1 = 0, s2 = 0;
        for (int w = 0; w < 4; ++w) { s0 += sd[w][0]; s1 += sd[w][1]; s2 += sd[w][2]; }
        partials[blockIdx.x * 3 + 0] = s0;
        partials[blockIdx.x * 3 + 1] = s1;
        partials[blockIdx.x * 3 + 2] = s2;
    }
}

__global__ __launch_bounds__(256)
void finish_kernel(const double* __restrict__ partials,
                   double* __restrict__ sums) {
    int t = threadIdx.x;
    double s0 = 0, s1 = 0, s2 = 0;
    for (int r = t; r < RED_BLOCKS; r += 256) {
        s0 += partials[r * 3 + 0];
        s1 += partials[r * 3 + 1];
        s2 += partials[r * 3 + 2];
    }
    for (int off = 32; off > 0; off >>= 1) {
        s0 += __shfl_down(s0, off);
        s1 += __shfl_down(s1, off);
        s2 += __shfl_down(s2, off);
    }
    __shared__ double sd[4][3];
    int wid = t >> 6, lane = t & 63;
    if (lane == 0) { sd[wid][0] = s0; sd[wid][1] = s1; sd[wid][2] = s2; }
    __syncthreads();
    if (t == 0) {
        double a = 0, b = 0, c = 0;
        for (int w = 0; w < 4; ++w) { a += sd[w][0]; b += sd[w][1]; c += sd[w][2]; }
        sums[0] = a; sums[1] = b; sums[2] = c;
    }
}

// ---------------------------------------------------------------------------
// Stage 5: final output (float4 quads). out = [x(2M), y(2M), nsx(2M), nsy(2M)]
// Region boundaries (1.5M, 1.6M, 2M) are multiples of 4 -> quads uniform.
// ---------------------------------------------------------------------------
__global__ __launch_bounds__(256)
void final_kernel(const float* __restrict__ pos,
                  const float* __restrict__ nsx,
                  const float* __restrict__ nsy,
                  const float2* __restrict__ S,
                  const double* __restrict__ sums,
                  float* __restrict__ out) {
    double sum_area  = sums[0];
    double sum_route = sums[1];
    double fill_old  = sums[2];
    double max_total = sum_area + fill_old;

    float scale = fminf(1.0f, (float)(max_total / fmax(sum_route, 1e-6)));
    float sum_new = (float)(scale * (float)sum_route);
    float fscale = sqrtf(fmaxf((float)max_total - sum_new, 0.0f) /
                         fmaxf((float)fill_old, 1e-6f));

    int q = blockIdx.x * blockDim.x + threadIdx.x;
    if (q >= N_NODES / 4) return;
    int i = 4 * q;

    float4 x4  = *reinterpret_cast<const float4*>(pos + i);
    float4 y4  = *reinterpret_cast<const float4*>(pos + N_NODES + i);
    float4 sx4 = *reinterpret_cast<const float4*>(nsx + i);
    float4 sy4 = *reinterpret_cast<const float4*>(nsy + i);

    float xs[4] = {x4.x, x4.y, x4.z, x4.w};
    float ys[4] = {y4.x, y4.y, y4.z, y4.w};
    float sxs[4] = {sx4.x, sx4.y, sx4.z, sx4.w};
    float sys[4] = {sy4.x, sy4.y, sy4.z, sy4.w};

    if (i < N_MOVABLE) {
        #pragma unroll
        for (int k = 0; k < 4; ++k) {
            int bx = bin_idx(xs[k] + 0.5f * sxs[k]);
            int by = bin_idx(ys[k] + 0.5f * sys[k]);
            float2 u2 = S[(size_t)bx * NB + by];
            float ratio = fminf(fmaxf(fmaxf(u2.x, u2.y), 0.5f), 2.0f);
            float area = sxs[k] * sys[k];
            float new_area = area * ratio * scale;
            float sr = sqrtf(new_area / fmaxf(area, 1e-6f));
            float sx_new = sxs[k] * sr, sy_new = sys[k] * sr;
            xs[k] = xs[k] + 0.5f * (sxs[k] - sx_new);
            ys[k] = ys[k] + 0.5f * (sys[k] - sy_new);
            sxs[k] = sx_new; sys[k] = sy_new;
        }
    } else if (i >= N_NODES - N_FILLER) {
        #pragma unroll
        for (int k = 0; k < 4; ++k) { sxs[k] *= fscale; sys[k] *= fscale; }
    }

    *reinterpret_cast<float4*>(out + i)               = make_float4(xs[0], xs[1], xs[2], xs[3]);
    *reinterpret_cast<float4*>(out + N_NODES + i)     = make_float4(ys[0], ys[1], ys[2], ys[3]);
    *reinterpret_cast<float4*>(out + 2 * N_NODES + i) = make_float4(sxs[0], sxs[1], sxs[2], sxs[3]);
    *reinterpret_cast<float4*>(out + 3 * N_NODES + i) = make_float4(sys[0], sys[1], sys[2], sys[3]);
}

// ---------------------------------------------------------------------------
extern "C" void kernel_launch(void* const* d_in, const int* in_sizes, int n_in,
                              void* d_out, int out_size, void* d_ws, size_t ws_size,
                              hipStream_t stream) {
    const float* pos         = (const float*)d_in[0];
    const float* pin_pos     = (const float*)d_in[1];
    const float* nsx         = (const float*)d_in[2];
    const float* nsy         = (const float*)d_in[3];
    const int*   flat_netpin = (const int*)d_in[4];
    float* out = (float*)d_out;

    const size_t pp_b   = (size_t)N_PINS * sizeof(float2);             // 48 MB
    const size_t slab_b = (size_t)NBUCKET * CAP * sizeof(float4);      // 40 MB
    const size_t dp_b   = (size_t)NMAPS * NB * NB * sizeof(float2);    // 8 MB
    const size_t s_b    = (size_t)NB * NB * sizeof(float2);            // 2 MB
    const size_t part_b = (size_t)RED_BLOCKS * 3 * sizeof(double);     // 24 KB
    const size_t gp_b   = 4096;

    // Primary layout: [pp(48) | slab(40) | g_ptr | ..]; Dp/S/partials/sums
    // overlay pp (dead after gather): 8+2+0.024 MB << 48 MB.
    const size_t need_primary = pp_b + slab_b + gp_b + 256;

    char* base = (char*)d_ws;
    bool packed = (ws_size >= need_primary);

    float2* pp; float4* slab; float2* Dp; float2* S;
    double* partials; double* sums; unsigned* g_ptr;
    if (packed) {
        pp       = (float2*)base;
        Dp       = (float2*)base;                       // overlay after gather
        S        = (float2*)(base + dp_b);
        partials = (double*)(base + dp_b + s_b);
        sums     = (double*)(base + dp_b + s_b + part_b);
        slab     = (float4*)(base + pp_b);
        g_ptr    = (unsigned*)(base + pp_b + slab_b);
    } else {
        pp       = nullptr;
        slab     = (float4*)base;
        Dp       = (float2*)(base + slab_b);
        S        = (float2*)(base + slab_b + dp_b);
        partials = (double*)(base + slab_b + dp_b + s_b);
        sums     = (double*)(base + slab_b + dp_b + s_b + part_b);
        g_ptr    = (unsigned*)(base + slab_b + dp_b + s_b + part_b + 64);
    }

    const int GB_BLOCKS = (N_NETS + NPB - 1) / NPB;    // 367
    if (packed) {
        pack_kernel<<<(N_PINS / 4 + 255) / 256, 256, 0, stream>>>(pin_pos, pp, g_ptr);
        gather_bin_kernel<true><<<GB_BLOCKS, 1024, 0, stream>>>(pin_pos, pp, flat_netpin, slab, g_ptr);
    } else {
        hipMemsetAsync(g_ptr, 0, NBUCKET * sizeof(unsigned), stream);
        gather_bin_kernel<false><<<GB_BLOCKS, 1024, 0, stream>>>(pin_pos, nullptr, flat_netpin, slab, g_ptr);
    }

    accum_kernel <<<NBUCKET * NSLICE, 256, 0, stream>>>(slab, g_ptr, Dp);
    scanA_kernel <<<NB, 512, 0, stream>>>(Dp, S);
    scanB_kernel <<<NB, 512, 0, stream>>>(S);
    reduce_kernel<<<RED_BLOCKS, 256, 0, stream>>>(pos, nsx, nsy, S, partials);
    finish_kernel<<<1, 256, 0, stream>>>(partials, sums);
    final_kernel <<<(N_NODES / 4 + 255) / 256, 256, 0, stream>>>(pos, nsx, nsy, S, sums, out);
}

// Round 8
// 238.950 us; speedup vs baseline: 3.3374x; 1.0134x over previous
//
#include <hip/hip_runtime.h>
#include <hip/hip_fp16.h>
#include <math.h>

#define N_NODES   2000000
#define N_MOVABLE 1500000
#define N_FILLER  400000
#define N_NETS    1500000
#define N_PINS    (N_NETS * 4)
#define NB        512                  // bins per axis (cropped map)
#define NT        16                   // tiles per axis
#define TILE      32                   // bins per tile axis
#define NBUCKET   (NT * NT)            // 256
#define CAP       10240                // slab capacity per bucket
#define NSLICE    4                    // record slices per tile
#define NMAPS     NSLICE               // partial diff maps (disjoint windows)
#define NPB       4096                 // nets per gather block (4 per thread)
#define RED_BLOCKS 1024

__device__ __forceinline__ int bin_idx(float v) {
    // BIN_W = 1000/512 = 1.953125 exactly; matches jnp floor(v / BIN_W)
    float b = floorf(v / 1.953125f);
    b = fminf(fmaxf(b, 0.0f), 511.0f);
    return (int)b;
}

// ---------------------------------------------------------------------------
// Stage 0: pack pin x/y halves into float2 (one line per gather) + zero g_ptr
// ---------------------------------------------------------------------------
__global__ void pack_kernel(const float* __restrict__ pin_pos,
                            float2* __restrict__ pp,
                            unsigned* __restrict__ g_ptr) {
    if (blockIdx.x == 0 && threadIdx.x < NBUCKET) g_ptr[threadIdx.x] = 0u;
    int i = blockIdx.x * blockDim.x + threadIdx.x;
    if (i >= N_PINS / 4) return;
    float4 a = reinterpret_cast<const float4*>(pin_pos)[i];
    float4 b = reinterpret_cast<const float4*>(pin_pos + N_PINS)[i];
    float4* o = reinterpret_cast<float4*>(pp + 4 * (size_t)i);
    o[0] = make_float4(a.x, b.x, a.y, b.y);
    o[1] = make_float4(a.z, b.z, a.w, b.w);
}

// ---------------------------------------------------------------------------
// Per-net 8-byte record:
//   .x = f16x2 {vh, vv}   (densities; bin geometry stays exact f32 below)
//   .y = blx | bly<<9 | (bhx+1-blx)<<18 | (bhy+1-bly)<<23   (9+9+5+5 bits)
// Span <= ceil(40/1.953125)+1 = 22 < 32 -> 5 bits suffice. Corner == 512 is
// representable (ax0+dx) and cropped by accum's window test.
// ---------------------------------------------------------------------------
template <bool PACKED>
__device__ __forceinline__ uint2 make_rec(const float* __restrict__ pin_pos,
                                          const float2* __restrict__ pp,
                                          int4 fp, int* bucket) {
    float2 p0, p1, p2, p3;
    if (PACKED) {
        p0 = pp[fp.x]; p1 = pp[fp.y]; p2 = pp[fp.z]; p3 = pp[fp.w];
    } else {
        p0 = make_float2(pin_pos[fp.x], pin_pos[N_PINS + fp.x]);
        p1 = make_float2(pin_pos[fp.y], pin_pos[N_PINS + fp.y]);
        p2 = make_float2(pin_pos[fp.z], pin_pos[N_PINS + fp.z]);
        p3 = make_float2(pin_pos[fp.w], pin_pos[N_PINS + fp.w]);
    }
    float xl = fminf(fminf(p0.x, p1.x), fminf(p2.x, p3.x));
    float xh = fmaxf(fmaxf(p0.x, p1.x), fmaxf(p2.x, p3.x));
    float yl = fminf(fminf(p0.y, p1.y), fminf(p2.y, p3.y));
    float yh = fmaxf(fmaxf(p0.y, p1.y), fmaxf(p2.y, p3.y));
    float bw = xh - xl, bh = yh - yl;
    float barea = fmaxf(bw * bh, 1e-6f);
    // fold /UNIT_H_CAP; clamp so degenerate bboxes can't overflow f16
    float vh = fminf((bw / barea) * (1.0f / 1.5f), 60000.0f);
    float vv = fminf((bh / barea) * (1.0f / 1.5f), 60000.0f);
    unsigned blx = bin_idx(xl), bhx = bin_idx(xh);
    unsigned bly = bin_idx(yl), bhy = bin_idx(yh);
    *bucket = (int)((bly >> 5) * NT + (blx >> 5));
    __half2 h = __float22half2_rn(make_float2(vh, vv));
    uint2 r;
    r.x = *reinterpret_cast<unsigned*>(&h);
    r.y = blx | (bly << 9) | ((bhx + 1 - blx) << 18) | ((bhy + 1 - bly) << 23);
    return r;
}

// ---------------------------------------------------------------------------
// Stage 1: gather + bucket (counting-sort into per-tile slabs), 4 nets/thread
// ---------------------------------------------------------------------------
template <bool PACKED>
__global__ __launch_bounds__(1024)
void gather_bin_kernel(const float* __restrict__ pin_pos,
                       const float2* __restrict__ pp,
                       const int*  __restrict__ fnp,
                       uint2* __restrict__ slab,
                       unsigned* __restrict__ g_ptr) {
    __shared__ unsigned hist[NBUCKET];
    __shared__ unsigned base[NBUCKET];
    int t = threadIdx.x;
    if (t < NBUCKET) hist[t] = 0;
    __syncthreads();

    int n0 = blockIdx.x * NPB + t;
    bool v[4]; int4 fp[4]; uint2 r[4]; int b[4]; unsigned rk[4];
    #pragma unroll
    for (int k = 0; k < 4; ++k) {
        int n = n0 + k * 1024;
        v[k] = (n < N_NETS);
        fp[k] = v[k] ? *reinterpret_cast<const int4*>(fnp + 4 * (size_t)n)
                     : make_int4(0, 0, 0, 0);
    }
    #pragma unroll
    for (int k = 0; k < 4; ++k) {
        b[k] = 0;
        if (v[k]) r[k] = make_rec<PACKED>(pin_pos, pp, fp[k], &b[k]);
    }
    #pragma unroll
    for (int k = 0; k < 4; ++k) {
        rk[k] = v[k] ? atomicAdd(&hist[b[k]], 1u) : 0u;
    }
    __syncthreads();
    if (t < NBUCKET) {
        unsigned c = hist[t];
        base[t] = c ? atomicAdd(&g_ptr[t], c) : 0u;
    }
    __syncthreads();
    #pragma unroll
    for (int k = 0; k < 4; ++k) {
        if (v[k]) {
            unsigned s = base[b[k]] + rk[k];
            if (s < CAP) slab[(size_t)b[k] * CAP + s] = r[k];
        }
    }
}

// ---------------------------------------------------------------------------
// Stage 2: per-tile accumulation in LDS. wg = tile*NSLICE + slice.
// Each wg reads slice [cnt*s/4, cnt*(s+1)/4) of its 4 source buckets
// ({tx-1,tx} x {ty-1,ty}: bbox span <= 22 bins), tests the 4 corners
// against its own 32x32 window, accumulates in 8 KB LDS, and writes the
// window to partial map `slice` with plain stores (windows are disjoint
// and tile the plane -> every map fully covered, no masks, no atomics).
// Corner coords ==512 drop out of every window (cropped).
// 4-deep load pipeline to cover slab-read latency.
// ---------------------------------------------------------------------------
__device__ __forceinline__ void rec_process(uint2 r, int x0, int y0,
                                            float2* acc) {
    float2 v = __half22float2(*reinterpret_cast<const __half2*>(&r.x));
    unsigned g = r.y;
    int ax0 = (int)(g & 511u);
    int ay0 = (int)((g >> 9) & 511u);
    int ax1 = ax0 + (int)((g >> 18) & 31u);
    int ay1 = ay0 + (int)((g >> 23) & 31u);
    int X0 = ax0 - x0, Y0 = ay0 - y0;
    int X1 = ax1 - x0, Y1 = ay1 - y0;
    bool iX0 = (unsigned)X0 < TILE, iX1 = (unsigned)X1 < TILE;
    bool iY0 = (unsigned)Y0 < TILE, iY1 = (unsigned)Y1 < TILE;
    if (iX0 && iY0) { atomicAdd(&acc[X0 * TILE + Y0].x,  v.x); atomicAdd(&acc[X0 * TILE + Y0].y,  v.y); }
    if (iX1 && iY0) { atomicAdd(&acc[X1 * TILE + Y0].x, -v.x); atomicAdd(&acc[X1 * TILE + Y0].y, -v.y); }
    if (iX0 && iY1) { atomicAdd(&acc[X0 * TILE + Y1].x, -v.x); atomicAdd(&acc[X0 * TILE + Y1].y, -v.y); }
    if (iX1 && iY1) { atomicAdd(&acc[X1 * TILE + Y1].x,  v.x); atomicAdd(&acc[X1 * TILE + Y1].y,  v.y); }
}

__global__ __launch_bounds__(256)
void accum_kernel(const uint2* __restrict__ slab,
                  const unsigned* __restrict__ g_cnt,
                  float2* __restrict__ Dp) {
    __shared__ float2 acc[TILE * TILE];       // 8 KB
    int wg = blockIdx.x;                       // 0..1023
    int sl = wg & (NSLICE - 1), tile = wg >> 2;
    int tx = tile & (NT - 1), ty = tile >> 4;
    int tid = threadIdx.x;

    for (int i = tid; i < TILE * TILE; i += 256) acc[i] = make_float2(0.f, 0.f);
    __syncthreads();

    int x0 = tx * TILE, y0 = ty * TILE;
    #pragma unroll
    for (int dy = -1; dy <= 0; ++dy) {
        int sy = ty + dy; if (sy < 0) continue;
        #pragma unroll
        for (int dx = -1; dx <= 0; ++dx) {
            int sx = tx + dx; if (sx < 0) continue;
            int sb = sy * NT + sx;
            unsigned cnt = min(g_cnt[sb], (unsigned)CAP);
            unsigned lo = (cnt * (unsigned)sl) >> 2;
            unsigned hi = (cnt * (unsigned)(sl + 1)) >> 2;
            const uint2* recs = slab + (size_t)sb * CAP;
            unsigned i = lo + tid;
            for (; i + 768 < hi; i += 1024) {        // 4-deep pipeline
                uint2 r0 = recs[i];
                uint2 r1 = recs[i + 256];
                uint2 r2 = recs[i + 512];
                uint2 r3 = recs[i + 768];
                rec_process(r0, x0, y0, acc);
                rec_process(r1, x0, y0, acc);
                rec_process(r2, x0, y0, acc);
                rec_process(r3, x0, y0, acc);
            }
            for (; i < hi; i += 256) rec_process(recs[i], x0, y0, acc);
        }
    }
    __syncthreads();

    float2* D = Dp + (size_t)sl * NB * NB;
    for (int i = tid; i < TILE * TILE; i += 256) {
        int X = i >> 5, Y = i & 31;
        D[(size_t)(x0 + X) * NB + (y0 + Y)] = acc[i];
    }
}

// ---------------------------------------------------------------------------
// Stage 3a: cumsum along y; sums the 4 slice maps on load (coalesced).
// ---------------------------------------------------------------------------
__global__ __launch_bounds__(512)
void scanA_kernel(const float2* __restrict__ Dp, float2* __restrict__ S) {
    __shared__ float2 s[NB];
    int x = blockIdx.x, t = threadIdx.x;
    float2 a = make_float2(0.f, 0.f);
    #pragma unroll
    for (int m = 0; m < NMAPS; ++m) {
        float2 v = Dp[(size_t)m * NB * NB + (size_t)x * NB + t];
        a.x += v.x; a.y += v.y;
    }
    s[t] = a;
    __syncthreads();
    for (int off = 1; off < NB; off <<= 1) {
        float2 u = s[t];
        if (t >= off) { float2 w = s[t - off]; u.x += w.x; u.y += w.y; }
        __syncthreads();
        s[t] = u;
        __syncthreads();
    }
    S[(size_t)x * NB + t] = s[t];
}

// Stage 3b: cumsum along x (strided single-map pass; 2 MB L2-resident)
__global__ __launch_bounds__(512)
void scanB_kernel(float2* __restrict__ S) {
    __shared__ float2 s[NB];
    int y = blockIdx.x, t = threadIdx.x;
    s[t] = S[(size_t)t * NB + y];
    __syncthreads();
    for (int off = 1; off < NB; off <<= 1) {
        float2 u = s[t];
        if (t >= off) { float2 w = s[t - off]; u.x += w.x; u.y += w.y; }
        __syncthreads();
        s[t] = u;
        __syncthreads();
    }
    S[(size_t)t * NB + y] = s[t];
}

// ---------------------------------------------------------------------------
// Stage 4: reductions (float4 quads) -> per-block partials, then finish
// ---------------------------------------------------------------------------
__global__ __launch_bounds__(256)
void reduce_kernel(const float* __restrict__ pos,
                   const float* __restrict__ nsx,
                   const float* __restrict__ nsy,
                   const float2* __restrict__ S,
                   double* __restrict__ partials) {
    const int MQ = N_MOVABLE / 4;            // 375000
    const int TQ = MQ + N_FILLER / 4;        // 475000
    double a_old = 0.0, a_route = 0.0, a_fill = 0.0;
    int stride = gridDim.x * blockDim.x;
    for (int q = blockIdx.x * blockDim.x + threadIdx.x; q < TQ; q += stride) {
        if (q < MQ) {
            int i = 4 * q;
            float4 x4  = *reinterpret_cast<const float4*>(pos + i);
            float4 y4  = *reinterpret_cast<const float4*>(pos + N_NODES + i);
            float4 sx4 = *reinterpret_cast<const float4*>(nsx + i);
            float4 sy4 = *reinterpret_cast<const float4*>(nsy + i);
            float xs[4] = {x4.x, x4.y, x4.z, x4.w};
            float ys[4] = {y4.x, y4.y, y4.z, y4.w};
            float sxs[4] = {sx4.x, sx4.y, sx4.z, sx4.w};
            float sys[4] = {sy4.x, sy4.y, sy4.z, sy4.w};
            #pragma unroll
            for (int k = 0; k < 4; ++k) {
                int bx = bin_idx(xs[k] + 0.5f * sxs[k]);
                int by = bin_idx(ys[k] + 0.5f * sys[k]);
                float2 u2 = S[(size_t)bx * NB + by];
                float ratio = fminf(fmaxf(fmaxf(u2.x, u2.y), 0.5f), 2.0f);
                float area = sxs[k] * sys[k];
                a_old += (double)area;
                a_route += (double)(area * ratio);
            }
        } else {
            int j = (N_NODES - N_FILLER) + 4 * (q - MQ);
            float4 sx4 = *reinterpret_cast<const float4*>(nsx + j);
            float4 sy4 = *reinterpret_cast<const float4*>(nsy + j);
            a_fill += (double)(sx4.x * sy4.x + sx4.y * sy4.y +
                               sx4.z * sy4.z + sx4.w * sy4.w);
        }
    }
    for (int off = 32; off > 0; off >>= 1) {
        a_old   += __shfl_down(a_old, off);
        a_route += __shfl_down(a_route, off);
        a_fill  += __shfl_down(a_fill, off);
    }
    __shared__ double sd[4][3];
    int wid = threadIdx.x >> 6, lane = threadIdx.x & 63;
    if (lane == 0) { sd[wid][0] = a_old; sd[wid][1] = a_route; sd[wid][2] = a_fill; }
    __syncthreads();
    if (threadIdx.x == 0) {
        double s0 = 0, s1 = 0, s2 = 0;
        for (int w = 0; w < 4; ++w) { s0 += sd[w][0]; s1 += sd[w][1]; s2 += sd[w][2]; }
        partials[blockIdx.x * 3 + 0] = s0;
        partials[blockIdx.x * 3 + 1] = s1;
        partials[blockIdx.x * 3 + 2] = s2;
    }
}

__global__ __launch_bounds__(256)
void finish_kernel(const double* __restrict__ partials,
                   double* __restrict__ sums) {
    int t = threadIdx.x;
    double s0 = 0, s1 = 0, s2 = 0;
    for (int r = t; r < RED_BLOCKS; r += 256) {
        s0 += partials[r * 3 + 0];
        s1 += partials[r * 3 + 1];
        s2 += partials[r * 3 + 2];
    }
    for (int off = 32; off > 0; off >>= 1) {
        s0 += __shfl_down(s0, off);
        s1 += __shfl_down(s1, off);
        s2 += __shfl_down(s2, off);
    }
    __shared__ double sd[4][3];
    int wid = t >> 6, lane = t & 63;
    if (lane == 0) { sd[wid][0] = s0; sd[wid][1] = s1; sd[wid][2] = s2; }
    __syncthreads();
    if (t == 0) {
        double a = 0, b = 0, c = 0;
        for (int w = 0; w < 4; ++w) { a += sd[w][0]; b += sd[w][1]; c += sd[w][2]; }
        sums[0] = a; sums[1] = b; sums[2] = c;
    }
}

// ---------------------------------------------------------------------------
// Stage 5: final output (float4 quads). out = [x(2M), y(2M), nsx(2M), nsy(2M)]
// Region boundaries (1.5M, 1.6M, 2M) are multiples of 4 -> quads uniform.
// ---------------------------------------------------------------------------
__global__ __launch_bounds__(256)
void final_kernel(const float* __restrict__ pos,
                  const float* __restrict__ nsx,
                  const float* __restrict__ nsy,
                  const float2* __restrict__ S,
                  const double* __restrict__ sums,
                  float* __restrict__ out) {
    double sum_area  = sums[0];
    double sum_route = sums[1];
    double fill_old  = sums[2];
    double max_total = sum_area + fill_old;

    float scale = fminf(1.0f, (float)(max_total / fmax(sum_route, 1e-6)));
    float sum_new = (float)(scale * (float)sum_route);
    float fscale = sqrtf(fmaxf((float)max_total - sum_new, 0.0f) /
                         fmaxf((float)fill_old, 1e-6f));

    int q = blockIdx.x * blockDim.x + threadIdx.x;
    if (q >= N_NODES / 4) return;
    int i = 4 * q;

    float4 x4  = *reinterpret_cast<const float4*>(pos + i);
    float4 y4  = *reinterpret_cast<const float4*>(pos + N_NODES + i);
    float4 sx4 = *reinterpret_cast<const float4*>(nsx + i);
    float4 sy4 = *reinterpret_cast<const float4*>(nsy + i);

    float xs[4] = {x4.x, x4.y, x4.z, x4.w};
    float ys[4] = {y4.x, y4.y, y4.z, y4.w};
    float sxs[4] = {sx4.x, sx4.y, sx4.z, sx4.w};
    float sys[4] = {sy4.x, sy4.y, sy4.z, sy4.w};

    if (i < N_MOVABLE) {
        #pragma unroll
        for (int k = 0; k < 4; ++k) {
            int bx = bin_idx(xs[k] + 0.5f * sxs[k]);
            int by = bin_idx(ys[k] + 0.5f * sys[k]);
            float2 u2 = S[(size_t)bx * NB + by];
            float ratio = fminf(fmaxf(fmaxf(u2.x, u2.y), 0.5f), 2.0f);
            float area = sxs[k] * sys[k];
            float new_area = area * ratio * scale;
            float sr = sqrtf(new_area / fmaxf(area, 1e-6f));
            float sx_new = sxs[k] * sr, sy_new = sys[k] * sr;
            xs[k] = xs[k] + 0.5f * (sxs[k] - sx_new);
            ys[k] = ys[k] + 0.5f * (sys[k] - sy_new);
            sxs[k] = sx_new; sys[k] = sy_new;
        }
    } else if (i >= N_NODES - N_FILLER) {
        #pragma unroll
        for (int k = 0; k < 4; ++k) { sxs[k] *= fscale; sys[k] *= fscale; }
    }

    *reinterpret_cast<float4*>(out + i)               = make_float4(xs[0], xs[1], xs[2], xs[3]);
    *reinterpret_cast<float4*>(out + N_NODES + i)     = make_float4(ys[0], ys[1], ys[2], ys[3]);
    *reinterpret_cast<float4*>(out + 2 * N_NODES + i) = make_float4(sxs[0], sxs[1], sxs[2], sxs[3]);
    *reinterpret_cast<float4*>(out + 3 * N_NODES + i) = make_float4(sys[0], sys[1], sys[2], sys[3]);
}

// ---------------------------------------------------------------------------
extern "C" void kernel_launch(void* const* d_in, const int* in_sizes, int n_in,
                              void* d_out, int out_size, void* d_ws, size_t ws_size,
                              hipStream_t stream) {
    const float* pos         = (const float*)d_in[0];
    const float* pin_pos     = (const float*)d_in[1];
    const float* nsx         = (const float*)d_in[2];
    const float* nsy         = (const float*)d_in[3];
    const int*   flat_netpin = (const int*)d_in[4];
    float* out = (float*)d_out;

    const size_t pp_b   = (size_t)N_PINS * sizeof(float2);             // 48 MB
    const size_t slab_b = (size_t)NBUCKET * CAP * sizeof(uint2);       // 20 MB
    const size_t dp_b   = (size_t)NMAPS * NB * NB * sizeof(float2);    // 8 MB
    const size_t s_b    = (size_t)NB * NB * sizeof(float2);            // 2 MB
    const size_t part_b = (size_t)RED_BLOCKS * 3 * sizeof(double);     // 24 KB
    const size_t gp_b   = 4096;

    // Primary layout: [pp(48) | slab(20) | g_ptr | ..]; Dp/S/partials/sums
    // overlay pp (dead after gather): 8+2+0.024 MB << 48 MB.
    const size_t need_primary = pp_b + slab_b + gp_b + 256;

    char* base = (char*)d_ws;
    bool packed = (ws_size >= need_primary);

    float2* pp; uint2* slab; float2* Dp; float2* S;
    double* partials; double* sums; unsigned* g_ptr;
    if (packed) {
        pp       = (float2*)base;
        Dp       = (float2*)base;                       // overlay after gather
        S        = (float2*)(base + dp_b);
        partials = (double*)(base + dp_b + s_b);
        sums     = (double*)(base + dp_b + s_b + part_b);
        slab     = (uint2*)(base + pp_b);
        g_ptr    = (unsigned*)(base + pp_b + slab_b);
    } else {
        pp       = nullptr;
        slab     = (uint2*)base;
        Dp       = (float2*)(base + slab_b);
        S        = (float2*)(base + slab_b + dp_b);
        partials = (double*)(base + slab_b + dp_b + s_b);
        sums     = (double*)(base + slab_b + dp_b + s_b + part_b);
        g_ptr    = (unsigned*)(base + slab_b + dp_b + s_b + part_b + 64);
    }

    const int GB_BLOCKS = (N_NETS + NPB - 1) / NPB;    // 367
    if (packed) {
        pack_kernel<<<(N_PINS / 4 + 255) / 256, 256, 0, stream>>>(pin_pos, pp, g_ptr);
        gather_bin_kernel<true><<<GB_BLOCKS, 1024, 0, stream>>>(pin_pos, pp, flat_netpin, slab, g_ptr);
    } else {
        hipMemsetAsync(g_ptr, 0, NBUCKET * sizeof(unsigned), stream);
        gather_bin_kernel<false><<<GB_BLOCKS, 1024, 0, stream>>>(pin_pos, nullptr, flat_netpin, slab, g_ptr);
    }

    accum_kernel <<<NBUCKET * NSLICE, 256, 0, stream>>>(slab, g_ptr, Dp);
    scanA_kernel <<<NB, 512, 0, stream>>>(Dp, S);
    scanB_kernel <<<NB, 512, 0, stream>>>(S);
    reduce_kernel<<<RED_BLOCKS, 256, 0, stream>>>(pos, nsx, nsy, S, partials);
    finish_kernel<<<1, 256, 0, stream>>>(partials, sums);
    final_kernel <<<(N_NODES / 4 + 255) / 256, 256, 0, stream>>>(pos, nsx, nsy, S, sums, out);
}